// Round 4
// baseline (193.462 us; speedup 1.0000x reference)
//
#include <hip/hip_runtime.h>

#define B_ 8
#define S_ 1024
#define D_ 1024
#define H_ 16
#define DH_ 64

typedef __attribute__((ext_vector_type(4))) float f32x4;
typedef __attribute__((ext_vector_type(8))) short short8;   // 8 bf16 bit-patterns

__device__ __forceinline__ unsigned short f32_to_bf16_rne(float f) {
    union { float f; unsigned int u; } c; c.f = f;
    unsigned int u = c.u;
    unsigned int r = u + 0x7FFFu + ((u >> 16) & 1u);
    return (unsigned short)(r >> 16);
}

__device__ __forceinline__ void gl_lds16(const unsigned short* g, const unsigned short* l) {
    __builtin_amdgcn_global_load_lds((const __attribute__((address_space(1))) unsigned int*)g,
                                     (__attribute__((address_space(3))) unsigned int*)l, 16, 0, 0);
}

// ---------------- merged f32 -> bf16 convert: x (4096 blocks) + Wq/Wk/Wv ----
__global__ __launch_bounds__(256) void cvt_all(const float* __restrict__ x,
                                               const float* __restrict__ Wq,
                                               const float* __restrict__ Wk,
                                               const float* __restrict__ Wv,
                                               unsigned short* __restrict__ xb,
                                               unsigned short* __restrict__ wb) {
    int bid = blockIdx.x;
    const float* src; unsigned short* dst; long i;
    if (bid < 4096) {
        src = x; dst = xb; i = (long)bid * 256 + threadIdx.x;
    } else {
        int wbid = bid - 4096;
        int z = wbid >> 9;                       // 512 blocks per weight matrix
        src = (z == 0) ? Wq : ((z == 1) ? Wk : Wv);
        dst = wb + (size_t)z * D_ * D_;
        i = (long)(wbid & 511) * 256 + threadIdx.x;
    }
    const float4* s4 = reinterpret_cast<const float4*>(src) + i * 2;
    float4 a = s4[0], b = s4[1];
    short8 o;
    o[0] = (short)f32_to_bf16_rne(a.x); o[1] = (short)f32_to_bf16_rne(a.y);
    o[2] = (short)f32_to_bf16_rne(a.z); o[3] = (short)f32_to_bf16_rne(a.w);
    o[4] = (short)f32_to_bf16_rne(b.x); o[5] = (short)f32_to_bf16_rne(b.y);
    o[6] = (short)f32_to_bf16_rne(b.z); o[7] = (short)f32_to_bf16_rne(b.w);
    reinterpret_cast<short8*>(dst)[i] = o;
}

// ---------------- QKV GEMM: 256x128 tile, 8 waves, triple-buffer depth-2 ----
// 256 blocks, XCD-owned m-slabs, z-loop inside (A-tile L2-reuse).
// Round-0 proven schedule (prev-session round-9): one phase per K-step,
// counted vmcnt(6), 1 barrier. Reverted verbatim after rounds 1-3 showed
// every multi-barrier/fused-acc variant spills or stalls worse (72.6/67.5/80.4
// vs 63.5 us).
// z==2 (V) writes DIRECTLY TRANSPOSED into Vt[bh*64+dh][s] (fused transpose).
__global__ __launch_bounds__(512, 1) void gemm_qkv(const unsigned short* __restrict__ X,
                                                   const unsigned short* __restrict__ Wall,
                                                   const float* __restrict__ bq,
                                                   const float* __restrict__ bk,
                                                   const float* __restrict__ bv,
                                                   const int* __restrict__ lengths,
                                                   unsigned short* __restrict__ QKV,
                                                   unsigned short* __restrict__ Vt) {
    extern __shared__ unsigned short smem[];   // 3 stages x (A 16384 + B 8192 shorts)
    const int STG = 24576;                     // shorts per stage (49152 B)

    const int bid = blockIdx.x;
    const int xcd = bid & 7, loc = bid >> 3;   // loc 0..31
    const int mt = xcd * 4 + (loc & 3);        // 0..31
    const int nt = loc >> 2;                   // 0..7
    const int m0 = mt * 256, n0 = nt * 128;
    const int tid = threadIdx.x;
    const int lane = tid & 63;
    const int w = tid >> 6;
    const int wm = (w >> 1) * 64, wn = (w & 1) * 64;

    int aoff[2][4], boff[2][4];
    #pragma unroll
    for (int ks = 0; ks < 2; ks++)
        #pragma unroll
        for (int i = 0; i < 4; i++) {
            int arow = wm + i * 16 + (lane & 15);
            aoff[ks][i] = arow * 64 + (((ks * 4 + (lane >> 4)) ^ (arow & 7)) * 8);
            int brow = wn + i * 16 + (lane & 15);
            boff[ks][i] = brow * 64 + (((ks * 4 + (lane >> 4)) ^ (brow & 7)) * 8);
        }

    for (int z = 0; z < 3; z++) {
        const unsigned short* Wz = Wall + (size_t)z * D_ * D_;
        const float* bias = (z == 0) ? bq : ((z == 1) ? bk : bv);

        const unsigned short* xsrc[4];
        const unsigned short* wsrc[2];
        #pragma unroll
        for (int p = 0; p < 4; p++) {
            int row = p * 64 + w * 8 + (lane >> 3);
            int slot = (lane & 7) ^ (row & 7);
            xsrc[p] = &X[(size_t)(m0 + row) * D_ + slot * 8];
        }
        #pragma unroll
        for (int p = 0; p < 2; p++) {
            int row = p * 64 + w * 8 + (lane >> 3);
            int slot = (lane & 7) ^ (row & 7);
            wsrc[p] = &Wz[(size_t)(n0 + row) * D_ + slot * 8];
        }

        auto stage = [&](int s) {
            unsigned short* ab = smem + s * STG;
            #pragma unroll
            for (int p = 0; p < 4; p++) {
                gl_lds16(xsrc[p], ab + (p * 512 + w * 64) * 8);
                xsrc[p] += 64;
            }
            unsigned short* bb = ab + 16384;
            #pragma unroll
            for (int p = 0; p < 2; p++) {
                gl_lds16(wsrc[p], bb + (p * 512 + w * 64) * 8);
                wsrc[p] += 64;
            }
        };

        f32x4 acc[4][4] = {};

        __syncthreads();          // protect LDS buffer recycling across z
        stage(0);
        stage(1);
        int cur = 0;
        for (int t = 0; t < 16; t++) {
            if (t < 15) asm volatile("s_waitcnt vmcnt(6)" ::: "memory");  // stage(t) landed, t+1 in flight
            else        asm volatile("s_waitcnt vmcnt(0)" ::: "memory");
            __builtin_amdgcn_s_barrier();
            if (t < 14) stage(cur ? cur - 1 : 2);   // buffer (t+2)%3
            const unsigned short* Ab = smem + cur * STG;
            const unsigned short* Bb = Ab + 16384;
            #pragma unroll
            for (int ks = 0; ks < 2; ks++) {
                short8 af[4], bf[4];
                #pragma unroll
                for (int i = 0; i < 4; i++) {
                    af[i] = *reinterpret_cast<const short8*>(&Ab[aoff[ks][i]]);
                    bf[i] = *reinterpret_cast<const short8*>(&Bb[boff[ks][i]]);
                }
                #pragma unroll
                for (int i = 0; i < 4; i++)
                    #pragma unroll
                    for (int j = 0; j < 4; j++)
                        acc[i][j] = __builtin_amdgcn_mfma_f32_16x16x32_bf16(af[i], bf[j], acc[i][j], 0, 0, 0);
            }
            cur = (cur == 2) ? 0 : cur + 1;
        }

        if (z == 2) {
            // V: write transposed, packed 4 bf16 (4 consecutive s) per store
            #pragma unroll
            for (int j = 0; j < 4; j++) {
                int ncol = n0 + wn + j * 16 + (lane & 15);
                float bval = bias[ncol];
                int len = (ncol < 512) ? lengths[ncol >> 6] : (1 << 30);
                int h = ncol >> 6, dh = ncol & 63;
                #pragma unroll
                for (int i = 0; i < 4; i++) {
                    int mbase = m0 + wm + i * 16 + ((lane >> 4) << 2);
                    int b = mbase >> 10, s = mbase & 1023;
                    unsigned short v4[4];
                    #pragma unroll
                    for (int r = 0; r < 4; r++) {
                        int m = mbase + r;
                        float v = acc[i][j][r] + bval;
                        if (m < S_ && ncol < 512 && m >= len) v = 0.f;  // batch-0-only mask bug repro
                        v4[r] = f32_to_bf16_rne(v);
                    }
                    *reinterpret_cast<uint2*>(&Vt[((size_t)((b * 16 + h) * 64 + dh)) * S_ + s]) =
                        *reinterpret_cast<uint2*>(v4);
                }
            }
        } else {
            unsigned short* Out = QKV + (size_t)z * (B_ * S_) * D_;
            #pragma unroll
            for (int j = 0; j < 4; j++) {
                int ncol = n0 + wn + j * 16 + (lane & 15);
                float bval = bias[ncol];
                int len = (ncol < 512) ? lengths[ncol >> 6] : (1 << 30);
                #pragma unroll
                for (int i = 0; i < 4; i++) {
                    int mbase = m0 + wm + i * 16 + ((lane >> 4) << 2);
                    #pragma unroll
                    for (int r = 0; r < 4; r++) {
                        int m = mbase + r;
                        float v = acc[i][j][r] + bval;
                        if (m < S_ && ncol < 512 && m >= len) v = 0.f;  // batch-0-only mask bug repro
                        Out[(size_t)m * D_ + ncol] = f32_to_bf16_rne(v);
                    }
                }
            }
        }
    }
}

// ---------------- attention: swapped-QK^T flash, in-register P via permlane ----
// qtile=128: each wave owns TWO 16-row q-groups sharing the staged K/V tile.
// NEW (this round): counted-vmcnt staging instead of __syncthreads full drain.
// K triple-buffered (prefetch-2), V double-buffered (prefetch-1, waited
// mid-body just before PV -- a full compute phase after issue). Raw s_barrier
// + literal vmcnt(4/2/0); no vmcnt(0) drain until the last iteration.
// LDS 3x8 + 2x8 = 40 KB -> 4 blocks/CU preserved.
__global__ __launch_bounds__(256, 4) void attn_kernel(const unsigned short* __restrict__ QKV,
                                                      const unsigned short* __restrict__ Vt,
                                                      unsigned short* __restrict__ Ctxb) {
    const int id = blockIdx.x;
    const int xcd = id & 7, seq = id >> 3;
    const int qt = seq & 7;                       // 8 q-tiles of 128 rows
    const int bh = ((seq >> 3) << 3) | xcd;
    const int b = bh >> 4, h = bh & 15;
    const int tid = threadIdx.x, lane = tid & 63, w = tid >> 6;
    const int qcol = lane & 15, g = lane >> 4;

    __shared__ unsigned short Ks[3][64 * 64];
    __shared__ unsigned short Vs[2][64 * 64];

    const unsigned short* Qg = QKV + (size_t)(b * S_) * D_ + h * DH_;
    const unsigned short* Kg = Qg + (size_t)(B_ * S_) * D_;
    const unsigned short* Vg = Vt + (size_t)bh * DH_ * S_;   // [dh][S]

    const int q0w = qt * 128 + w * 16;            // group A rows; group B = +64

    short8 qfA[2], qfB[2];
    {
        const unsigned short* qa = Qg + (size_t)(q0w + qcol) * D_ + g * 8;
        qfA[0] = *reinterpret_cast<const short8*>(qa);
        qfA[1] = *reinterpret_cast<const short8*>(qa + 32);
        const unsigned short* qb = Qg + (size_t)(q0w + 64 + qcol) * D_ + g * 8;
        qfB[0] = *reinterpret_cast<const short8*>(qb);
        qfB[1] = *reinterpret_cast<const short8*>(qb + 32);
    }

    float lA = 0.f, lB = 0.f;
    f32x4 caccA[4] = {}, caccB[4] = {};

    const unsigned short* kp0; const unsigned short* kp1;
    const unsigned short* vp0; const unsigned short* vp1;
    {
        int i0 = (w * 2 + 0) * 64 + lane;
        int r0 = i0 >> 3, c0 = (i0 & 7) ^ (r0 & 7);
        kp0 = Kg + (size_t)r0 * D_ + c0 * 8;
        vp0 = Vg + (size_t)r0 * S_ + c0 * 8;
        int i1 = (w * 2 + 1) * 64 + lane;
        int r1 = i1 >> 3, c1 = (i1 & 7) ^ (r1 & 7);
        kp1 = Kg + (size_t)r1 * D_ + c1 * 8;
        vp1 = Vg + (size_t)r1 * S_ + c1 * 8;
    }
    unsigned short* kd0[3] = { &Ks[0][(w * 2 + 0) * 512], &Ks[1][(w * 2 + 0) * 512], &Ks[2][(w * 2 + 0) * 512] };
    unsigned short* kd1[3] = { &Ks[0][(w * 2 + 1) * 512], &Ks[1][(w * 2 + 1) * 512], &Ks[2][(w * 2 + 1) * 512] };
    unsigned short* vd0[2] = { &Vs[0][(w * 2 + 0) * 512], &Vs[1][(w * 2 + 0) * 512] };
    unsigned short* vd1[2] = { &Vs[0][(w * 2 + 1) * 512], &Vs[1][(w * 2 + 1) * 512] };

    auto stageK = [&](int bf) {
        gl_lds16(kp0, kd0[bf]); gl_lds16(kp1, kd1[bf]);
        kp0 += 64 * D_; kp1 += 64 * D_;
    };
    auto stageV = [&](int bf) {
        gl_lds16(vp0, vd0[bf]); gl_lds16(vp1, vd1[bf]);
        vp0 += 64; vp1 += 64;
    };

    const float C2 = 0.04508422004083421f;   // log2(e)/32  (scale = 1/sqrt(1024))
    const float MB = 11.54156171223618f;     // 8*log2(e): fixed softmax shift M=8
    // Fixed-max softmax: shift-invariant; scaled scores bounded so
    // exp2(s*C2 - MB) cannot overflow. No running max / rescale needed.

    union F8 { unsigned int u[4]; short8 s; };

    // prologue: K(0), K(1), V(0) in flight; require K(0) landed (leaves 4)
    stageK(0); stageK(1); stageV(0);
    asm volatile("s_waitcnt vmcnt(4)" ::: "memory");

    for (int t = 0; t < 16; t++) {
        // top barrier: publishes K(t) (each wave drained its K(t) at t-1's
        // mid-wait; prologue wait for t=0)
        __builtin_amdgcn_s_barrier();
        asm volatile("" ::: "memory");
        if (t < 14) stageK(t == 0 ? 2 : ((t + 2) % 3));
        if (t < 15) stageV((t + 1) & 1);
        const unsigned short* Kb = Ks[t % 3];
        const unsigned short* Vb = Vs[t & 1];

        // S^T = K Q^T for both q-groups, kf read once
        f32x4 sA[4] = {}, sB[4] = {};
        __builtin_amdgcn_s_setprio(1);
        #pragma unroll
        for (int ks = 0; ks < 2; ks++) {
            #pragma unroll
            for (int ni = 0; ni < 4; ni++) {
                int krow = ni * 16 + qcol;
                int slot = (ks * 4 + g) ^ (krow & 7);
                short8 kf = *reinterpret_cast<const short8*>(&Kb[krow * 64 + slot * 8]);
                sA[ni] = __builtin_amdgcn_mfma_f32_16x16x32_bf16(kf, qfA[ks], sA[ni], 0, 0, 0);
                sB[ni] = __builtin_amdgcn_mfma_f32_16x16x32_bf16(kf, qfB[ks], sB[ni], 0, 0, 0);
            }
        }
        __builtin_amdgcn_s_setprio(0);

        F8 pkA0, pkA1, pkB0, pkB1;
        {   // softmax + in-register P routing, group A
            float p[16];
            #pragma unroll
            for (int ni = 0; ni < 4; ni++)
                #pragma unroll
                for (int r = 0; r < 4; r++)
                    p[ni * 4 + r] = __builtin_amdgcn_exp2f(__builtin_fmaf(sA[ni][r], C2, -MB));
            lA += ((p[0] + p[1]) + (p[2] + p[3])) + ((p[4] + p[5]) + (p[6] + p[7]))
                + ((p[8] + p[9]) + (p[10] + p[11])) + ((p[12] + p[13]) + (p[14] + p[15]));
            unsigned int Wa[4], Wb[4];
            #pragma unroll
            for (int ni = 0; ni < 4; ni++) {
                asm("v_cvt_pk_bf16_f32 %0, %1, %2" : "=v"(Wa[ni]) : "v"(p[ni * 4 + 0]), "v"(p[ni * 4 + 1]));
                asm("v_cvt_pk_bf16_f32 %0, %1, %2" : "=v"(Wb[ni]) : "v"(p[ni * 4 + 2]), "v"(p[ni * 4 + 3]));
            }
            unsigned int a0 = Wa[0], a1 = Wa[1], b0 = Wb[0], b1 = Wb[1];
            unsigned int c0 = Wa[2], c1 = Wa[3], d0 = Wb[2], d1 = Wb[3];
            asm("v_permlane32_swap_b32 %0, %1" : "+v"(a0), "+v"(a1));
            asm("v_permlane16_swap_b32 %0, %1" : "+v"(a0), "+v"(a1));
            asm("v_permlane32_swap_b32 %0, %1" : "+v"(b0), "+v"(b1));
            asm("v_permlane16_swap_b32 %0, %1" : "+v"(b0), "+v"(b1));
            asm("v_permlane32_swap_b32 %0, %1" : "+v"(c0), "+v"(c1));
            asm("v_permlane16_swap_b32 %0, %1" : "+v"(c0), "+v"(c1));
            asm("v_permlane32_swap_b32 %0, %1" : "+v"(d0), "+v"(d1));
            asm("v_permlane16_swap_b32 %0, %1" : "+v"(d0), "+v"(d1));
            pkA0.u[0] = a0; pkA0.u[1] = b0; pkA0.u[2] = a1; pkA0.u[3] = b1;
            pkA1.u[0] = c0; pkA1.u[1] = d0; pkA1.u[2] = c1; pkA1.u[3] = d1;
        }
        {   // group B
            float p[16];
            #pragma unroll
            for (int ni = 0; ni < 4; ni++)
                #pragma unroll
                for (int r = 0; r < 4; r++)
                    p[ni * 4 + r] = __builtin_amdgcn_exp2f(__builtin_fmaf(sB[ni][r], C2, -MB));
            lB += ((p[0] + p[1]) + (p[2] + p[3])) + ((p[4] + p[5]) + (p[6] + p[7]))
                + ((p[8] + p[9]) + (p[10] + p[11])) + ((p[12] + p[13]) + (p[14] + p[15]));
            unsigned int Wa[4], Wb[4];
            #pragma unroll
            for (int ni = 0; ni < 4; ni++) {
                asm("v_cvt_pk_bf16_f32 %0, %1, %2" : "=v"(Wa[ni]) : "v"(p[ni * 4 + 0]), "v"(p[ni * 4 + 1]));
                asm("v_cvt_pk_bf16_f32 %0, %1, %2" : "=v"(Wb[ni]) : "v"(p[ni * 4 + 2]), "v"(p[ni * 4 + 3]));
            }
            unsigned int a0 = Wa[0], a1 = Wa[1], b0 = Wb[0], b1 = Wb[1];
            unsigned int c0 = Wa[2], c1 = Wa[3], d0 = Wb[2], d1 = Wb[3];
            asm("v_permlane32_swap_b32 %0, %1" : "+v"(a0), "+v"(a1));
            asm("v_permlane16_swap_b32 %0, %1" : "+v"(a0), "+v"(a1));
            asm("v_permlane32_swap_b32 %0, %1" : "+v"(b0), "+v"(b1));
            asm("v_permlane16_swap_b32 %0, %1" : "+v"(b0), "+v"(b1));
            asm("v_permlane32_swap_b32 %0, %1" : "+v"(c0), "+v"(c1));
            asm("v_permlane16_swap_b32 %0, %1" : "+v"(c0), "+v"(c1));
            asm("v_permlane32_swap_b32 %0, %1" : "+v"(d0), "+v"(d1));
            asm("v_permlane16_swap_b32 %0, %1" : "+v"(d0), "+v"(d1));
            pkB0.u[0] = a0; pkB0.u[1] = b0; pkB0.u[2] = a1; pkB0.u[3] = b1;
            pkB1.u[0] = c0; pkB1.u[1] = d0; pkB1.u[2] = c1; pkB1.u[3] = d1;
        }

        // mid wait: V(t) landed (counted; leaves K(t+2),V(t+1) in flight)
        if (t < 14)       asm volatile("s_waitcnt vmcnt(4)" ::: "memory");
        else if (t == 14) asm volatile("s_waitcnt vmcnt(2)" ::: "memory");
        else              asm volatile("s_waitcnt vmcnt(0)" ::: "memory");
        __builtin_amdgcn_s_barrier();
        asm volatile("" ::: "memory");

        // PV for both groups, vf read once
        __builtin_amdgcn_s_setprio(1);
        #pragma unroll
        for (int ks = 0; ks < 2; ks++) {
            short8 pfA = ks ? pkA1.s : pkA0.s;
            short8 pfB = ks ? pkB1.s : pkB0.s;
            #pragma unroll
            for (int ni = 0; ni < 4; ni++) {
                int vrow = ni * 16 + qcol;
                int slot = (ks * 4 + g) ^ (vrow & 7);
                short8 vf = *reinterpret_cast<const short8*>(&Vb[vrow * 64 + slot * 8]);
                caccA[ni] = __builtin_amdgcn_mfma_f32_16x16x32_bf16(pfA, vf, caccA[ni], 0, 0, 0);
                caccB[ni] = __builtin_amdgcn_mfma_f32_16x16x32_bf16(pfB, vf, caccB[ni], 0, 0, 0);
            }
        }
        __builtin_amdgcn_s_setprio(0);
    }

    lA += __shfl_xor(lA, 16, 64);
    lA += __shfl_xor(lA, 32, 64);
    lB += __shfl_xor(lB, 16, 64);
    lB += __shfl_xor(lB, 32, 64);

    #pragma unroll
    for (int r = 0; r < 4; r++) {
        float la = __shfl(lA, (g << 2) + r, 64);
        float lb = __shfl(lB, (g << 2) + r, 64);
        float invA = 1.f / la, invB = 1.f / lb;
        int qrowA = q0w + (g << 2) + r;
        int qrowB = qrowA + 64;
        #pragma unroll
        for (int ni = 0; ni < 4; ni++) {
            int dh = ni * 16 + qcol;
            Ctxb[(size_t)(b * S_ + qrowA) * D_ + h * DH_ + dh] = f32_to_bf16_rne(caccA[ni][r] * invA);
            Ctxb[(size_t)(b * S_ + qrowB) * D_ + h * DH_ + dh] = f32_to_bf16_rne(caccB[ni][r] * invB);
        }
    }
}

// ---------------- residual + LayerNorm (bf16 ctx + bf16 x) ----------------
__global__ __launch_bounds__(256) void ln_kernel(const unsigned short* __restrict__ Ctxb,
                                                 const unsigned short* __restrict__ Xb,
                                                 const float* __restrict__ gamma,
                                                 const float* __restrict__ beta,
                                                 float* __restrict__ out) {
    const int row = blockIdx.x;
    const int tid = threadIdx.x;
    const int lane = tid & 63, w = tid >> 6;

    ushort4 c4 = reinterpret_cast<const ushort4*>(Ctxb + (size_t)row * D_)[tid];
    ushort4 x4 = reinterpret_cast<const ushort4*>(Xb + (size_t)row * D_)[tid];
    float4 v;
    v.x = __uint_as_float((unsigned)c4.x << 16) + __uint_as_float((unsigned)x4.x << 16);
    v.y = __uint_as_float((unsigned)c4.y << 16) + __uint_as_float((unsigned)x4.y << 16);
    v.z = __uint_as_float((unsigned)c4.z << 16) + __uint_as_float((unsigned)x4.z << 16);
    v.w = __uint_as_float((unsigned)c4.w << 16) + __uint_as_float((unsigned)x4.w << 16);

    float s = v.x + v.y + v.z + v.w;
    float ss = v.x * v.x + v.y * v.y + v.z * v.z + v.w * v.w;
    for (int off = 1; off < 64; off <<= 1) {
        s += __shfl_xor(s, off, 64);
        ss += __shfl_xor(ss, off, 64);
    }
    __shared__ float sbuf[4], ssbuf[4];
    if (lane == 0) { sbuf[w] = s; ssbuf[w] = ss; }
    __syncthreads();
    s = sbuf[0] + sbuf[1] + sbuf[2] + sbuf[3];
    ss = ssbuf[0] + ssbuf[1] + ssbuf[2] + ssbuf[3];

    float mean = s * (1.f / D_);
    float var = ss * (1.f / D_) - mean * mean;
    float rstd = rsqrtf(var + 1e-5f);

    const float4 gm = reinterpret_cast<const float4*>(gamma)[tid];
    const float4 bt = reinterpret_cast<const float4*>(beta)[tid];
    float4 o;
    o.x = (v.x - mean) * rstd * gm.x + bt.x;
    o.y = (v.y - mean) * rstd * gm.y + bt.y;
    o.z = (v.z - mean) * rstd * gm.z + bt.z;
    o.w = (v.w - mean) * rstd * gm.w + bt.w;
    reinterpret_cast<float4*>(out + (size_t)row * D_)[tid] = o;
}

extern "C" void kernel_launch(void* const* d_in, const int* in_sizes, int n_in,
                              void* d_out, int out_size, void* d_ws, size_t ws_size,
                              hipStream_t stream) {
    const float* x       = (const float*)d_in[0];
    const int*   lengths = (const int*)d_in[1];
    const float* Wq      = (const float*)d_in[2];
    const float* bq      = (const float*)d_in[3];
    const float* Wk      = (const float*)d_in[4];
    const float* bk      = (const float*)d_in[5];
    const float* Wv      = (const float*)d_in[6];
    const float* bv      = (const float*)d_in[7];
    const float* gamma   = (const float*)d_in[8];
    const float* beta    = (const float*)d_in[9];
    float* out = (float*)d_out;

    char* ws = (char*)d_ws;
    unsigned short* xb    = (unsigned short*)(ws);                 // 16 MB
    unsigned short* Wball = (unsigned short*)(ws + 16777216);      // 6 MB
    unsigned short* QKV   = (unsigned short*)(ws + 23068672);      // 32 MB (Q,K only)
    unsigned short* Vt    = (unsigned short*)(ws + 56623104);      // 16 MB
    unsigned short* Ctxb  = (unsigned short*)(ws + 73400320);      // 16 MB (end 90.2 MB)

    // allow 144 KB dynamic LDS for gemm_qkv (host-side, capture-safe, idempotent)
    (void)hipFuncSetAttribute((const void*)gemm_qkv,
                              hipFuncAttributeMaxDynamicSharedMemorySize, 147456);

    cvt_all<<<5632, 256, 0, stream>>>(x, Wq, Wk, Wv, xb, Wball);

    gemm_qkv<<<256, 512, 147456, stream>>>(xb, Wball, bq, bk, bv, lengths, QKV, Vt);

    attn_kernel<<<1024, 256, 0, stream>>>(QKV, Vt, Ctxb);

    ln_kernel<<<8192, 256, 0, stream>>>(Ctxb, xb, gamma, beta, out);
}

// Round 5
// 128.642 us; speedup vs baseline: 1.5039x; 1.5039x over previous
//
#include <hip/hip_runtime.h>

#define B_ 8
#define S_ 1024
#define D_ 1024
#define H_ 16
#define DH_ 64

typedef __attribute__((ext_vector_type(4))) float f32x4;
typedef __attribute__((ext_vector_type(8))) short short8;   // 8 bf16 bit-patterns

__device__ __forceinline__ unsigned short f32_to_bf16_rne(float f) {
    union { float f; unsigned int u; } c; c.f = f;
    unsigned int u = c.u;
    unsigned int r = u + 0x7FFFu + ((u >> 16) & 1u);
    return (unsigned short)(r >> 16);
}

__device__ __forceinline__ void gl_lds16(const unsigned short* g, const unsigned short* l) {
    __builtin_amdgcn_global_load_lds((const __attribute__((address_space(1))) unsigned int*)g,
                                     (__attribute__((address_space(3))) unsigned int*)l, 16, 0, 0);
}

// ---------------- merged f32 -> bf16 convert: x (4096 blocks) + Wq/Wk/Wv ----
__global__ __launch_bounds__(256) void cvt_all(const float* __restrict__ x,
                                               const float* __restrict__ Wq,
                                               const float* __restrict__ Wk,
                                               const float* __restrict__ Wv,
                                               unsigned short* __restrict__ xb,
                                               unsigned short* __restrict__ wb) {
    int bid = blockIdx.x;
    const float* src; unsigned short* dst; long i;
    if (bid < 4096) {
        src = x; dst = xb; i = (long)bid * 256 + threadIdx.x;
    } else {
        int wbid = bid - 4096;
        int z = wbid >> 9;                       // 512 blocks per weight matrix
        src = (z == 0) ? Wq : ((z == 1) ? Wk : Wv);
        dst = wb + (size_t)z * D_ * D_;
        i = (long)(wbid & 511) * 256 + threadIdx.x;
    }
    const float4* s4 = reinterpret_cast<const float4*>(src) + i * 2;
    float4 a = s4[0], b = s4[1];
    short8 o;
    o[0] = (short)f32_to_bf16_rne(a.x); o[1] = (short)f32_to_bf16_rne(a.y);
    o[2] = (short)f32_to_bf16_rne(a.z); o[3] = (short)f32_to_bf16_rne(a.w);
    o[4] = (short)f32_to_bf16_rne(b.x); o[5] = (short)f32_to_bf16_rne(b.y);
    o[6] = (short)f32_to_bf16_rne(b.z); o[7] = (short)f32_to_bf16_rne(b.w);
    reinterpret_cast<short8*>(dst)[i] = o;
}

// ---------------- QKV GEMM: 256x128 tile, 8 waves, triple-buffer depth-2 ----
// 256 blocks, XCD-owned m-slabs, z-loop inside (A-tile L2-reuse).
// Round-0 proven schedule: one phase per K-step, counted vmcnt(6), 1 barrier.
// Kept verbatim: rounds 1-3 showed every multi-barrier/fused-acc variant
// spills or stalls worse (72.6/67.5/80.4 vs 63.5 us).
// z==2 (V) writes DIRECTLY TRANSPOSED into Vt[bh*64+dh][s] (fused transpose).
__global__ __launch_bounds__(512, 1) void gemm_qkv(const unsigned short* __restrict__ X,
                                                   const unsigned short* __restrict__ Wall,
                                                   const float* __restrict__ bq,
                                                   const float* __restrict__ bk,
                                                   const float* __restrict__ bv,
                                                   const int* __restrict__ lengths,
                                                   unsigned short* __restrict__ QKV,
                                                   unsigned short* __restrict__ Vt) {
    extern __shared__ unsigned short smem[];   // 3 stages x (A 16384 + B 8192 shorts)
    const int STG = 24576;                     // shorts per stage (49152 B)

    const int bid = blockIdx.x;
    const int xcd = bid & 7, loc = bid >> 3;   // loc 0..31
    const int mt = xcd * 4 + (loc & 3);        // 0..31
    const int nt = loc >> 2;                   // 0..7
    const int m0 = mt * 256, n0 = nt * 128;
    const int tid = threadIdx.x;
    const int lane = tid & 63;
    const int w = tid >> 6;
    const int wm = (w >> 1) * 64, wn = (w & 1) * 64;

    int aoff[2][4], boff[2][4];
    #pragma unroll
    for (int ks = 0; ks < 2; ks++)
        #pragma unroll
        for (int i = 0; i < 4; i++) {
            int arow = wm + i * 16 + (lane & 15);
            aoff[ks][i] = arow * 64 + (((ks * 4 + (lane >> 4)) ^ (arow & 7)) * 8);
            int brow = wn + i * 16 + (lane & 15);
            boff[ks][i] = brow * 64 + (((ks * 4 + (lane >> 4)) ^ (brow & 7)) * 8);
        }

    for (int z = 0; z < 3; z++) {
        const unsigned short* Wz = Wall + (size_t)z * D_ * D_;
        const float* bias = (z == 0) ? bq : ((z == 1) ? bk : bv);

        const unsigned short* xsrc[4];
        const unsigned short* wsrc[2];
        #pragma unroll
        for (int p = 0; p < 4; p++) {
            int row = p * 64 + w * 8 + (lane >> 3);
            int slot = (lane & 7) ^ (row & 7);
            xsrc[p] = &X[(size_t)(m0 + row) * D_ + slot * 8];
        }
        #pragma unroll
        for (int p = 0; p < 2; p++) {
            int row = p * 64 + w * 8 + (lane >> 3);
            int slot = (lane & 7) ^ (row & 7);
            wsrc[p] = &Wz[(size_t)(n0 + row) * D_ + slot * 8];
        }

        auto stage = [&](int s) {
            unsigned short* ab = smem + s * STG;
            #pragma unroll
            for (int p = 0; p < 4; p++) {
                gl_lds16(xsrc[p], ab + (p * 512 + w * 64) * 8);
                xsrc[p] += 64;
            }
            unsigned short* bb = ab + 16384;
            #pragma unroll
            for (int p = 0; p < 2; p++) {
                gl_lds16(wsrc[p], bb + (p * 512 + w * 64) * 8);
                wsrc[p] += 64;
            }
        };

        f32x4 acc[4][4] = {};

        __syncthreads();          // protect LDS buffer recycling across z
        stage(0);
        stage(1);
        int cur = 0;
        for (int t = 0; t < 16; t++) {
            if (t < 15) asm volatile("s_waitcnt vmcnt(6)" ::: "memory");  // stage(t) landed, t+1 in flight
            else        asm volatile("s_waitcnt vmcnt(0)" ::: "memory");
            __builtin_amdgcn_s_barrier();
            if (t < 14) stage(cur ? cur - 1 : 2);   // buffer (t+2)%3
            const unsigned short* Ab = smem + cur * STG;
            const unsigned short* Bb = Ab + 16384;
            #pragma unroll
            for (int ks = 0; ks < 2; ks++) {
                short8 af[4], bf[4];
                #pragma unroll
                for (int i = 0; i < 4; i++) {
                    af[i] = *reinterpret_cast<const short8*>(&Ab[aoff[ks][i]]);
                    bf[i] = *reinterpret_cast<const short8*>(&Bb[boff[ks][i]]);
                }
                #pragma unroll
                for (int i = 0; i < 4; i++)
                    #pragma unroll
                    for (int j = 0; j < 4; j++)
                        acc[i][j] = __builtin_amdgcn_mfma_f32_16x16x32_bf16(af[i], bf[j], acc[i][j], 0, 0, 0);
            }
            cur = (cur == 2) ? 0 : cur + 1;
        }

        if (z == 2) {
            // V: write transposed, packed 4 bf16 (4 consecutive s) per store
            #pragma unroll
            for (int j = 0; j < 4; j++) {
                int ncol = n0 + wn + j * 16 + (lane & 15);
                float bval = bias[ncol];
                int len = (ncol < 512) ? lengths[ncol >> 6] : (1 << 30);
                int h = ncol >> 6, dh = ncol & 63;
                #pragma unroll
                for (int i = 0; i < 4; i++) {
                    int mbase = m0 + wm + i * 16 + ((lane >> 4) << 2);
                    int b = mbase >> 10, s = mbase & 1023;
                    unsigned short v4[4];
                    #pragma unroll
                    for (int r = 0; r < 4; r++) {
                        int m = mbase + r;
                        float v = acc[i][j][r] + bval;
                        if (m < S_ && ncol < 512 && m >= len) v = 0.f;  // batch-0-only mask bug repro
                        v4[r] = f32_to_bf16_rne(v);
                    }
                    *reinterpret_cast<uint2*>(&Vt[((size_t)((b * 16 + h) * 64 + dh)) * S_ + s]) =
                        *reinterpret_cast<uint2*>(v4);
                }
            }
        } else {
            unsigned short* Out = QKV + (size_t)z * (B_ * S_) * D_;
            #pragma unroll
            for (int j = 0; j < 4; j++) {
                int ncol = n0 + wn + j * 16 + (lane & 15);
                float bval = bias[ncol];
                int len = (ncol < 512) ? lengths[ncol >> 6] : (1 << 30);
                #pragma unroll
                for (int i = 0; i < 4; i++) {
                    int mbase = m0 + wm + i * 16 + ((lane >> 4) << 2);
                    #pragma unroll
                    for (int r = 0; r < 4; r++) {
                        int m = mbase + r;
                        float v = acc[i][j][r] + bval;
                        if (m < S_ && ncol < 512 && m >= len) v = 0.f;  // batch-0-only mask bug repro
                        Out[(size_t)m * D_ + ncol] = f32_to_bf16_rne(v);
                    }
                }
            }
        }
    }
}

// ---------------- attention: swapped-QK^T flash, in-register P via permlane ----
// Round-0 per-wave schedule kept VERBATIM (the __syncthreads lockstep is
// load-bearing: it aligns blocks sharing a (b,h) so K/V hit L2 -- round-4's
// counted-vmcnt variant destroyed it, FETCH 300MB, 3x slower).
// NEW geometry only: 8 waves/block, q-tile 256 (2 groups/wave at +0/+128),
// 512 blocks (4 per bh, same-XCD). Staging per wave halves (1 K + 1 V chunk);
// barrier cost per q-row halves; LDS stays 32 KB; 2 blocks/CU exact.
__global__ __launch_bounds__(512, 4) void attn_kernel(const unsigned short* __restrict__ QKV,
                                                      const unsigned short* __restrict__ Vt,
                                                      unsigned short* __restrict__ Ctxb) {
    const int id = blockIdx.x;
    const int xcd = id & 7, seq = id >> 3;
    const int qt = seq & 3;                       // 4 q-tiles of 256 rows
    const int bh = ((seq >> 2) << 3) | xcd;
    const int b = bh >> 4, h = bh & 15;
    const int tid = threadIdx.x, lane = tid & 63, w = tid >> 6;   // w 0..7
    const int qcol = lane & 15, g = lane >> 4;

    __shared__ unsigned short Ks[2][64 * 64];
    __shared__ unsigned short Vs[2][64 * 64];

    const unsigned short* Qg = QKV + (size_t)(b * S_) * D_ + h * DH_;
    const unsigned short* Kg = Qg + (size_t)(B_ * S_) * D_;
    const unsigned short* Vg = Vt + (size_t)bh * DH_ * S_;   // [dh][S]

    const int q0w = qt * 256 + w * 16;            // group A rows; group B = +128

    short8 qfA[2], qfB[2];
    {
        const unsigned short* qa = Qg + (size_t)(q0w + qcol) * D_ + g * 8;
        qfA[0] = *reinterpret_cast<const short8*>(qa);
        qfA[1] = *reinterpret_cast<const short8*>(qa + 32);
        const unsigned short* qb = Qg + (size_t)(q0w + 128 + qcol) * D_ + g * 8;
        qfB[0] = *reinterpret_cast<const short8*>(qb);
        qfB[1] = *reinterpret_cast<const short8*>(qb + 32);
    }

    float lA = 0.f, lB = 0.f;
    f32x4 caccA[4] = {}, caccB[4] = {};

    const unsigned short* kp0; const unsigned short* vp0;
    {
        int i0 = w * 64 + lane;                   // chunk w, 512 positions
        int r0 = i0 >> 3, c0 = (i0 & 7) ^ (r0 & 7);
        kp0 = Kg + (size_t)r0 * D_ + c0 * 8;
        vp0 = Vg + (size_t)r0 * S_ + c0 * 8;
    }
    unsigned short* kd0[2] = { &Ks[0][w * 512], &Ks[1][w * 512] };
    unsigned short* vd0[2] = { &Vs[0][w * 512], &Vs[1][w * 512] };

    auto stage = [&](int bf) {
        gl_lds16(kp0, kd0[bf]);
        gl_lds16(vp0, vd0[bf]);
        kp0 += 64 * D_;
        vp0 += 64;
    };

    const float C2 = 0.04508422004083421f;   // log2(e)/32  (scale = 1/sqrt(1024))
    const float MB = 11.54156171223618f;     // 8*log2(e): fixed softmax shift M=8
    // Fixed-max softmax: shift-invariant; scaled scores bounded so
    // exp2(s*C2 - MB) cannot overflow. No running max / rescale needed.

    union F8 { unsigned int u[4]; short8 s; };

    stage(0);
    #pragma unroll 2
    for (int t = 0; t < 16; t++) {
        __syncthreads();
        if (t < 15) stage((t + 1) & 1);
        const unsigned short* Kb = Ks[t & 1];
        const unsigned short* Vb = Vs[t & 1];

        // S^T = K Q^T for both q-groups, kf read once
        f32x4 sA[4] = {}, sB[4] = {};
        __builtin_amdgcn_s_setprio(1);
        #pragma unroll
        for (int ks = 0; ks < 2; ks++) {
            #pragma unroll
            for (int ni = 0; ni < 4; ni++) {
                int krow = ni * 16 + qcol;
                int slot = (ks * 4 + g) ^ (krow & 7);
                short8 kf = *reinterpret_cast<const short8*>(&Kb[krow * 64 + slot * 8]);
                sA[ni] = __builtin_amdgcn_mfma_f32_16x16x32_bf16(kf, qfA[ks], sA[ni], 0, 0, 0);
                sB[ni] = __builtin_amdgcn_mfma_f32_16x16x32_bf16(kf, qfB[ks], sB[ni], 0, 0, 0);
            }
        }
        __builtin_amdgcn_s_setprio(0);

        F8 pkA0, pkA1, pkB0, pkB1;
        {   // softmax + in-register P routing, group A
            float p[16];
            #pragma unroll
            for (int ni = 0; ni < 4; ni++)
                #pragma unroll
                for (int r = 0; r < 4; r++)
                    p[ni * 4 + r] = __builtin_amdgcn_exp2f(__builtin_fmaf(sA[ni][r], C2, -MB));
            lA += ((p[0] + p[1]) + (p[2] + p[3])) + ((p[4] + p[5]) + (p[6] + p[7]))
                + ((p[8] + p[9]) + (p[10] + p[11])) + ((p[12] + p[13]) + (p[14] + p[15]));
            unsigned int Wa[4], Wb[4];
            #pragma unroll
            for (int ni = 0; ni < 4; ni++) {
                asm("v_cvt_pk_bf16_f32 %0, %1, %2" : "=v"(Wa[ni]) : "v"(p[ni * 4 + 0]), "v"(p[ni * 4 + 1]));
                asm("v_cvt_pk_bf16_f32 %0, %1, %2" : "=v"(Wb[ni]) : "v"(p[ni * 4 + 2]), "v"(p[ni * 4 + 3]));
            }
            unsigned int a0 = Wa[0], a1 = Wa[1], b0 = Wb[0], b1 = Wb[1];
            unsigned int c0 = Wa[2], c1 = Wa[3], d0 = Wb[2], d1 = Wb[3];
            asm("v_permlane32_swap_b32 %0, %1" : "+v"(a0), "+v"(a1));
            asm("v_permlane16_swap_b32 %0, %1" : "+v"(a0), "+v"(a1));
            asm("v_permlane32_swap_b32 %0, %1" : "+v"(b0), "+v"(b1));
            asm("v_permlane16_swap_b32 %0, %1" : "+v"(b0), "+v"(b1));
            asm("v_permlane32_swap_b32 %0, %1" : "+v"(c0), "+v"(c1));
            asm("v_permlane16_swap_b32 %0, %1" : "+v"(c0), "+v"(c1));
            asm("v_permlane32_swap_b32 %0, %1" : "+v"(d0), "+v"(d1));
            asm("v_permlane16_swap_b32 %0, %1" : "+v"(d0), "+v"(d1));
            pkA0.u[0] = a0; pkA0.u[1] = b0; pkA0.u[2] = a1; pkA0.u[3] = b1;
            pkA1.u[0] = c0; pkA1.u[1] = d0; pkA1.u[2] = c1; pkA1.u[3] = d1;
        }
        {   // group B
            float p[16];
            #pragma unroll
            for (int ni = 0; ni < 4; ni++)
                #pragma unroll
                for (int r = 0; r < 4; r++)
                    p[ni * 4 + r] = __builtin_amdgcn_exp2f(__builtin_fmaf(sB[ni][r], C2, -MB));
            lB += ((p[0] + p[1]) + (p[2] + p[3])) + ((p[4] + p[5]) + (p[6] + p[7]))
                + ((p[8] + p[9]) + (p[10] + p[11])) + ((p[12] + p[13]) + (p[14] + p[15]));
            unsigned int Wa[4], Wb[4];
            #pragma unroll
            for (int ni = 0; ni < 4; ni++) {
                asm("v_cvt_pk_bf16_f32 %0, %1, %2" : "=v"(Wa[ni]) : "v"(p[ni * 4 + 0]), "v"(p[ni * 4 + 1]));
                asm("v_cvt_pk_bf16_f32 %0, %1, %2" : "=v"(Wb[ni]) : "v"(p[ni * 4 + 2]), "v"(p[ni * 4 + 3]));
            }
            unsigned int a0 = Wa[0], a1 = Wa[1], b0 = Wb[0], b1 = Wb[1];
            unsigned int c0 = Wa[2], c1 = Wa[3], d0 = Wb[2], d1 = Wb[3];
            asm("v_permlane32_swap_b32 %0, %1" : "+v"(a0), "+v"(a1));
            asm("v_permlane16_swap_b32 %0, %1" : "+v"(a0), "+v"(a1));
            asm("v_permlane32_swap_b32 %0, %1" : "+v"(b0), "+v"(b1));
            asm("v_permlane16_swap_b32 %0, %1" : "+v"(b0), "+v"(b1));
            asm("v_permlane32_swap_b32 %0, %1" : "+v"(c0), "+v"(c1));
            asm("v_permlane16_swap_b32 %0, %1" : "+v"(c0), "+v"(c1));
            asm("v_permlane32_swap_b32 %0, %1" : "+v"(d0), "+v"(d1));
            asm("v_permlane16_swap_b32 %0, %1" : "+v"(d0), "+v"(d1));
            pkB0.u[0] = a0; pkB0.u[1] = b0; pkB0.u[2] = a1; pkB0.u[3] = b1;
            pkB1.u[0] = c0; pkB1.u[1] = d0; pkB1.u[2] = c1; pkB1.u[3] = d1;
        }

        // PV for both groups, vf read once
        __builtin_amdgcn_s_setprio(1);
        #pragma unroll
        for (int ks = 0; ks < 2; ks++) {
            short8 pfA = ks ? pkA1.s : pkA0.s;
            short8 pfB = ks ? pkB1.s : pkB0.s;
            #pragma unroll
            for (int ni = 0; ni < 4; ni++) {
                int vrow = ni * 16 + qcol;
                int slot = (ks * 4 + g) ^ (vrow & 7);
                short8 vf = *reinterpret_cast<const short8*>(&Vb[vrow * 64 + slot * 8]);
                caccA[ni] = __builtin_amdgcn_mfma_f32_16x16x32_bf16(pfA, vf, caccA[ni], 0, 0, 0);
                caccB[ni] = __builtin_amdgcn_mfma_f32_16x16x32_bf16(pfB, vf, caccB[ni], 0, 0, 0);
            }
        }
        __builtin_amdgcn_s_setprio(0);
    }

    lA += __shfl_xor(lA, 16, 64);
    lA += __shfl_xor(lA, 32, 64);
    lB += __shfl_xor(lB, 16, 64);
    lB += __shfl_xor(lB, 32, 64);

    #pragma unroll
    for (int r = 0; r < 4; r++) {
        float la = __shfl(lA, (g << 2) + r, 64);
        float lb = __shfl(lB, (g << 2) + r, 64);
        float invA = 1.f / la, invB = 1.f / lb;
        int qrowA = q0w + (g << 2) + r;
        int qrowB = qrowA + 128;
        #pragma unroll
        for (int ni = 0; ni < 4; ni++) {
            int dh = ni * 16 + qcol;
            Ctxb[(size_t)(b * S_ + qrowA) * D_ + h * DH_ + dh] = f32_to_bf16_rne(caccA[ni][r] * invA);
            Ctxb[(size_t)(b * S_ + qrowB) * D_ + h * DH_ + dh] = f32_to_bf16_rne(caccB[ni][r] * invB);
        }
    }
}

// ---------------- residual + LayerNorm (bf16 ctx + bf16 x) ----------------
__global__ __launch_bounds__(256) void ln_kernel(const unsigned short* __restrict__ Ctxb,
                                                 const unsigned short* __restrict__ Xb,
                                                 const float* __restrict__ gamma,
                                                 const float* __restrict__ beta,
                                                 float* __restrict__ out) {
    const int row = blockIdx.x;
    const int tid = threadIdx.x;
    const int lane = tid & 63, w = tid >> 6;

    ushort4 c4 = reinterpret_cast<const ushort4*>(Ctxb + (size_t)row * D_)[tid];
    ushort4 x4 = reinterpret_cast<const ushort4*>(Xb + (size_t)row * D_)[tid];
    float4 v;
    v.x = __uint_as_float((unsigned)c4.x << 16) + __uint_as_float((unsigned)x4.x << 16);
    v.y = __uint_as_float((unsigned)c4.y << 16) + __uint_as_float((unsigned)x4.y << 16);
    v.z = __uint_as_float((unsigned)c4.z << 16) + __uint_as_float((unsigned)x4.z << 16);
    v.w = __uint_as_float((unsigned)c4.w << 16) + __uint_as_float((unsigned)x4.w << 16);

    float s = v.x + v.y + v.z + v.w;
    float ss = v.x * v.x + v.y * v.y + v.z * v.z + v.w * v.w;
    for (int off = 1; off < 64; off <<= 1) {
        s += __shfl_xor(s, off, 64);
        ss += __shfl_xor(ss, off, 64);
    }
    __shared__ float sbuf[4], ssbuf[4];
    if (lane == 0) { sbuf[w] = s; ssbuf[w] = ss; }
    __syncthreads();
    s = sbuf[0] + sbuf[1] + sbuf[2] + sbuf[3];
    ss = ssbuf[0] + ssbuf[1] + ssbuf[2] + ssbuf[3];

    float mean = s * (1.f / D_);
    float var = ss * (1.f / D_) - mean * mean;
    float rstd = rsqrtf(var + 1e-5f);

    const float4 gm = reinterpret_cast<const float4*>(gamma)[tid];
    const float4 bt = reinterpret_cast<const float4*>(beta)[tid];
    float4 o;
    o.x = (v.x - mean) * rstd * gm.x + bt.x;
    o.y = (v.y - mean) * rstd * gm.y + bt.y;
    o.z = (v.z - mean) * rstd * gm.z + bt.z;
    o.w = (v.w - mean) * rstd * gm.w + bt.w;
    reinterpret_cast<float4*>(out + (size_t)row * D_)[tid] = o;
}

extern "C" void kernel_launch(void* const* d_in, const int* in_sizes, int n_in,
                              void* d_out, int out_size, void* d_ws, size_t ws_size,
                              hipStream_t stream) {
    const float* x       = (const float*)d_in[0];
    const int*   lengths = (const int*)d_in[1];
    const float* Wq      = (const float*)d_in[2];
    const float* bq      = (const float*)d_in[3];
    const float* Wk      = (const float*)d_in[4];
    const float* bk      = (const float*)d_in[5];
    const float* Wv      = (const float*)d_in[6];
    const float* bv      = (const float*)d_in[7];
    const float* gamma   = (const float*)d_in[8];
    const float* beta    = (const float*)d_in[9];
    float* out = (float*)d_out;

    char* ws = (char*)d_ws;
    unsigned short* xb    = (unsigned short*)(ws);                 // 16 MB
    unsigned short* Wball = (unsigned short*)(ws + 16777216);      // 6 MB
    unsigned short* QKV   = (unsigned short*)(ws + 23068672);      // 32 MB (Q,K only)
    unsigned short* Vt    = (unsigned short*)(ws + 56623104);      // 16 MB
    unsigned short* Ctxb  = (unsigned short*)(ws + 73400320);      // 16 MB (end 90.2 MB)

    // allow 144 KB dynamic LDS for gemm_qkv (host-side, capture-safe, idempotent)
    (void)hipFuncSetAttribute((const void*)gemm_qkv,
                              hipFuncAttributeMaxDynamicSharedMemorySize, 147456);

    cvt_all<<<5632, 256, 0, stream>>>(x, Wq, Wk, Wv, xb, Wball);

    gemm_qkv<<<256, 512, 147456, stream>>>(xb, Wball, bq, bk, bv, lengths, QKV, Vt);

    attn_kernel<<<512, 512, 0, stream>>>(QKV, Vt, Ctxb);

    ln_kernel<<<8192, 256, 0, stream>>>(Ctxb, xb, gamma, beta, out);
}

// Round 6
// 128.591 us; speedup vs baseline: 1.5045x; 1.0004x over previous
//
#include <hip/hip_runtime.h>

#define B_ 8
#define S_ 1024
#define D_ 1024
#define H_ 16
#define DH_ 64

typedef __attribute__((ext_vector_type(4))) float f32x4;
typedef __attribute__((ext_vector_type(8))) short short8;   // 8 bf16 bit-patterns

__device__ __forceinline__ unsigned short f32_to_bf16_rne(float f) {
    union { float f; unsigned int u; } c; c.f = f;
    unsigned int u = c.u;
    unsigned int r = u + 0x7FFFu + ((u >> 16) & 1u);
    return (unsigned short)(r >> 16);
}

__device__ __forceinline__ void gl_lds16(const unsigned short* g, const unsigned short* l) {
    __builtin_amdgcn_global_load_lds((const __attribute__((address_space(1))) unsigned int*)g,
                                     (__attribute__((address_space(3))) unsigned int*)l, 16, 0, 0);
}

// ---------------- merged f32 -> bf16 convert: x (4096 blocks) + Wq/Wk/Wv ----
__global__ __launch_bounds__(256) void cvt_all(const float* __restrict__ x,
                                               const float* __restrict__ Wq,
                                               const float* __restrict__ Wk,
                                               const float* __restrict__ Wv,
                                               unsigned short* __restrict__ xb,
                                               unsigned short* __restrict__ wb) {
    int bid = blockIdx.x;
    const float* src; unsigned short* dst; long i;
    if (bid < 4096) {
        src = x; dst = xb; i = (long)bid * 256 + threadIdx.x;
    } else {
        int wbid = bid - 4096;
        int z = wbid >> 9;                       // 512 blocks per weight matrix
        src = (z == 0) ? Wq : ((z == 1) ? Wk : Wv);
        dst = wb + (size_t)z * D_ * D_;
        i = (long)(wbid & 511) * 256 + threadIdx.x;
    }
    const float4* s4 = reinterpret_cast<const float4*>(src) + i * 2;
    float4 a = s4[0], b = s4[1];
    short8 o;
    o[0] = (short)f32_to_bf16_rne(a.x); o[1] = (short)f32_to_bf16_rne(a.y);
    o[2] = (short)f32_to_bf16_rne(a.z); o[3] = (short)f32_to_bf16_rne(a.w);
    o[4] = (short)f32_to_bf16_rne(b.x); o[5] = (short)f32_to_bf16_rne(b.y);
    o[6] = (short)f32_to_bf16_rne(b.z); o[7] = (short)f32_to_bf16_rne(b.w);
    reinterpret_cast<short8*>(dst)[i] = o;
}

// ---------------- QKV GEMM: 256x128 tile, 8 waves, triple-buffer depth-2 ----
// 256 blocks, XCD-owned m-slabs, z-loop inside (A-tile L2-reuse).
// Round-0 proven schedule: one phase per K-step, counted vmcnt(6), 1 barrier.
// Kept verbatim: rounds 1-3 showed every multi-barrier/fused-acc variant
// spills or stalls worse (72.6/67.5/80.4 vs 63.5 us).
// z==2 (V) writes DIRECTLY TRANSPOSED into Vt[bh*64+dh][s] (fused transpose).
__global__ __launch_bounds__(512, 1) void gemm_qkv(const unsigned short* __restrict__ X,
                                                   const unsigned short* __restrict__ Wall,
                                                   const float* __restrict__ bq,
                                                   const float* __restrict__ bk,
                                                   const float* __restrict__ bv,
                                                   const int* __restrict__ lengths,
                                                   unsigned short* __restrict__ QKV,
                                                   unsigned short* __restrict__ Vt) {
    extern __shared__ unsigned short smem[];   // 3 stages x (A 16384 + B 8192 shorts)
    const int STG = 24576;                     // shorts per stage (49152 B)

    const int bid = blockIdx.x;
    const int xcd = bid & 7, loc = bid >> 3;   // loc 0..31
    const int mt = xcd * 4 + (loc & 3);        // 0..31
    const int nt = loc >> 2;                   // 0..7
    const int m0 = mt * 256, n0 = nt * 128;
    const int tid = threadIdx.x;
    const int lane = tid & 63;
    const int w = tid >> 6;
    const int wm = (w >> 1) * 64, wn = (w & 1) * 64;

    int aoff[2][4], boff[2][4];
    #pragma unroll
    for (int ks = 0; ks < 2; ks++)
        #pragma unroll
        for (int i = 0; i < 4; i++) {
            int arow = wm + i * 16 + (lane & 15);
            aoff[ks][i] = arow * 64 + (((ks * 4 + (lane >> 4)) ^ (arow & 7)) * 8);
            int brow = wn + i * 16 + (lane & 15);
            boff[ks][i] = brow * 64 + (((ks * 4 + (lane >> 4)) ^ (brow & 7)) * 8);
        }

    for (int z = 0; z < 3; z++) {
        const unsigned short* Wz = Wall + (size_t)z * D_ * D_;
        const float* bias = (z == 0) ? bq : ((z == 1) ? bk : bv);

        const unsigned short* xsrc[4];
        const unsigned short* wsrc[2];
        #pragma unroll
        for (int p = 0; p < 4; p++) {
            int row = p * 64 + w * 8 + (lane >> 3);
            int slot = (lane & 7) ^ (row & 7);
            xsrc[p] = &X[(size_t)(m0 + row) * D_ + slot * 8];
        }
        #pragma unroll
        for (int p = 0; p < 2; p++) {
            int row = p * 64 + w * 8 + (lane >> 3);
            int slot = (lane & 7) ^ (row & 7);
            wsrc[p] = &Wz[(size_t)(n0 + row) * D_ + slot * 8];
        }

        auto stage = [&](int s) {
            unsigned short* ab = smem + s * STG;
            #pragma unroll
            for (int p = 0; p < 4; p++) {
                gl_lds16(xsrc[p], ab + (p * 512 + w * 64) * 8);
                xsrc[p] += 64;
            }
            unsigned short* bb = ab + 16384;
            #pragma unroll
            for (int p = 0; p < 2; p++) {
                gl_lds16(wsrc[p], bb + (p * 512 + w * 64) * 8);
                wsrc[p] += 64;
            }
        };

        f32x4 acc[4][4] = {};

        __syncthreads();          // protect LDS buffer recycling across z
        stage(0);
        stage(1);
        int cur = 0;
        for (int t = 0; t < 16; t++) {
            if (t < 15) asm volatile("s_waitcnt vmcnt(6)" ::: "memory");  // stage(t) landed, t+1 in flight
            else        asm volatile("s_waitcnt vmcnt(0)" ::: "memory");
            __builtin_amdgcn_s_barrier();
            if (t < 14) stage(cur ? cur - 1 : 2);   // buffer (t+2)%3
            const unsigned short* Ab = smem + cur * STG;
            const unsigned short* Bb = Ab + 16384;
            #pragma unroll
            for (int ks = 0; ks < 2; ks++) {
                short8 af[4], bf[4];
                #pragma unroll
                for (int i = 0; i < 4; i++) {
                    af[i] = *reinterpret_cast<const short8*>(&Ab[aoff[ks][i]]);
                    bf[i] = *reinterpret_cast<const short8*>(&Bb[boff[ks][i]]);
                }
                #pragma unroll
                for (int i = 0; i < 4; i++)
                    #pragma unroll
                    for (int j = 0; j < 4; j++)
                        acc[i][j] = __builtin_amdgcn_mfma_f32_16x16x32_bf16(af[i], bf[j], acc[i][j], 0, 0, 0);
            }
            cur = (cur == 2) ? 0 : cur + 1;
        }

        if (z == 2) {
            // V: write transposed, packed 4 bf16 (4 consecutive s) per store
            #pragma unroll
            for (int j = 0; j < 4; j++) {
                int ncol = n0 + wn + j * 16 + (lane & 15);
                float bval = bias[ncol];
                int len = (ncol < 512) ? lengths[ncol >> 6] : (1 << 30);
                int h = ncol >> 6, dh = ncol & 63;
                #pragma unroll
                for (int i = 0; i < 4; i++) {
                    int mbase = m0 + wm + i * 16 + ((lane >> 4) << 2);
                    int b = mbase >> 10, s = mbase & 1023;
                    unsigned short v4[4];
                    #pragma unroll
                    for (int r = 0; r < 4; r++) {
                        int m = mbase + r;
                        float v = acc[i][j][r] + bval;
                        if (m < S_ && ncol < 512 && m >= len) v = 0.f;  // batch-0-only mask bug repro
                        v4[r] = f32_to_bf16_rne(v);
                    }
                    *reinterpret_cast<uint2*>(&Vt[((size_t)((b * 16 + h) * 64 + dh)) * S_ + s]) =
                        *reinterpret_cast<uint2*>(v4);
                }
            }
        } else {
            unsigned short* Out = QKV + (size_t)z * (B_ * S_) * D_;
            #pragma unroll
            for (int j = 0; j < 4; j++) {
                int ncol = n0 + wn + j * 16 + (lane & 15);
                float bval = bias[ncol];
                int len = (ncol < 512) ? lengths[ncol >> 6] : (1 << 30);
                #pragma unroll
                for (int i = 0; i < 4; i++) {
                    int mbase = m0 + wm + i * 16 + ((lane >> 4) << 2);
                    #pragma unroll
                    for (int r = 0; r < 4; r++) {
                        int m = mbase + r;
                        float v = acc[i][j][r] + bval;
                        if (m < S_ && ncol < 512 && m >= len) v = 0.f;  // batch-0-only mask bug repro
                        Out[(size_t)m * D_ + ncol] = f32_to_bf16_rne(v);
                    }
                }
            }
        }
    }
}

// ---------------- attention: swapped-QK^T flash, in-register P via permlane ----
// Round-0 schedule kept VERBATIM (__syncthreads lockstep is load-bearing for
// L2 K/V sharing -- r4 counted-vmcnt variant: FETCH 300MB, 3x slower).
// NEW: 4 q-groups per wave (was 2). Each kf/vf LDS fragment read once feeds
// 4 MFMAs -> per-CU LDS-read pipe time halves; MFMA/VALU totals unchanged;
// 4 independent chains per fragment double per-wave ILP (compensates the
// 2-waves/SIMD occupancy). 256 thr, 4 waves, q-tile 256/block, 512 blocks
// (4 per bh, same-XCD). VGPR ~190 -> launch_bounds(256,2) caps at 256 (no
// spill; r1/r3 spills were at the 128 cap).
__global__ __launch_bounds__(256, 2) void attn_kernel(const unsigned short* __restrict__ QKV,
                                                      const unsigned short* __restrict__ Vt,
                                                      unsigned short* __restrict__ Ctxb) {
    const int id = blockIdx.x;
    const int xcd = id & 7, seq = id >> 3;
    const int qt = seq & 3;                       // 4 q-tiles of 256 rows
    const int bh = ((seq >> 2) << 3) | xcd;
    const int b = bh >> 4, h = bh & 15;
    const int tid = threadIdx.x, lane = tid & 63, w = tid >> 6;   // w 0..3
    const int qcol = lane & 15, g = lane >> 4;

    __shared__ unsigned short Ks[2][64 * 64];
    __shared__ unsigned short Vs[2][64 * 64];

    const unsigned short* Qg = QKV + (size_t)(b * S_) * D_ + h * DH_;
    const unsigned short* Kg = Qg + (size_t)(B_ * S_) * D_;
    const unsigned short* Vg = Vt + (size_t)bh * DH_ * S_;   // [dh][S]

    const int q0w = qt * 256 + w * 16;            // group gr at +gr*64

    short8 qf[4][2];
    #pragma unroll
    for (int gr = 0; gr < 4; gr++) {
        const unsigned short* qa = Qg + (size_t)(q0w + gr * 64 + qcol) * D_ + g * 8;
        qf[gr][0] = *reinterpret_cast<const short8*>(qa);
        qf[gr][1] = *reinterpret_cast<const short8*>(qa + 32);
    }

    float l[4] = {};
    f32x4 cacc[4][4] = {};

    const unsigned short* kp0; const unsigned short* kp1;
    const unsigned short* vp0; const unsigned short* vp1;
    {
        int i0 = (w * 2 + 0) * 64 + lane;
        int r0 = i0 >> 3, c0 = (i0 & 7) ^ (r0 & 7);
        kp0 = Kg + (size_t)r0 * D_ + c0 * 8;
        vp0 = Vg + (size_t)r0 * S_ + c0 * 8;
        int i1 = (w * 2 + 1) * 64 + lane;
        int r1 = i1 >> 3, c1 = (i1 & 7) ^ (r1 & 7);
        kp1 = Kg + (size_t)r1 * D_ + c1 * 8;
        vp1 = Vg + (size_t)r1 * S_ + c1 * 8;
    }
    unsigned short* kd0[2] = { &Ks[0][(w * 2 + 0) * 512], &Ks[1][(w * 2 + 0) * 512] };
    unsigned short* kd1[2] = { &Ks[0][(w * 2 + 1) * 512], &Ks[1][(w * 2 + 1) * 512] };
    unsigned short* vd0[2] = { &Vs[0][(w * 2 + 0) * 512], &Vs[1][(w * 2 + 0) * 512] };
    unsigned short* vd1[2] = { &Vs[0][(w * 2 + 1) * 512], &Vs[1][(w * 2 + 1) * 512] };

    auto stage = [&](int bf) {
        gl_lds16(kp0, kd0[bf]); gl_lds16(kp1, kd1[bf]);
        gl_lds16(vp0, vd0[bf]); gl_lds16(vp1, vd1[bf]);
        kp0 += 64 * D_; kp1 += 64 * D_;
        vp0 += 64;      vp1 += 64;
    };

    const float C2 = 0.04508422004083421f;   // log2(e)/32  (scale = 1/sqrt(1024))
    const float MB = 11.54156171223618f;     // 8*log2(e): fixed softmax shift M=8
    // Fixed-max softmax: shift-invariant; scaled scores bounded so
    // exp2(s*C2 - MB) cannot overflow. No running max / rescale needed.

    union F8 { unsigned int u[4]; short8 s; };

    stage(0);
    for (int t = 0; t < 16; t++) {
        __syncthreads();
        if (t < 15) stage((t + 1) & 1);
        const unsigned short* Kb = Ks[t & 1];
        const unsigned short* Vb = Vs[t & 1];

        // S^T = K Q^T for all 4 q-groups, kf read once
        f32x4 s[4][4] = {};
        __builtin_amdgcn_s_setprio(1);
        #pragma unroll
        for (int ks = 0; ks < 2; ks++) {
            #pragma unroll
            for (int ni = 0; ni < 4; ni++) {
                int krow = ni * 16 + qcol;
                int slot = (ks * 4 + g) ^ (krow & 7);
                short8 kf = *reinterpret_cast<const short8*>(&Kb[krow * 64 + slot * 8]);
                #pragma unroll
                for (int gr = 0; gr < 4; gr++)
                    s[gr][ni] = __builtin_amdgcn_mfma_f32_16x16x32_bf16(kf, qf[gr][ks], s[gr][ni], 0, 0, 0);
            }
        }
        __builtin_amdgcn_s_setprio(0);

        F8 pk[4][2];
        #pragma unroll
        for (int gr = 0; gr < 4; gr++) {   // softmax + in-register P routing
            float p[16];
            #pragma unroll
            for (int ni = 0; ni < 4; ni++)
                #pragma unroll
                for (int r = 0; r < 4; r++)
                    p[ni * 4 + r] = __builtin_amdgcn_exp2f(__builtin_fmaf(s[gr][ni][r], C2, -MB));
            l[gr] += ((p[0] + p[1]) + (p[2] + p[3])) + ((p[4] + p[5]) + (p[6] + p[7]))
                   + ((p[8] + p[9]) + (p[10] + p[11])) + ((p[12] + p[13]) + (p[14] + p[15]));
            unsigned int Wa[4], Wb[4];
            #pragma unroll
            for (int ni = 0; ni < 4; ni++) {
                asm("v_cvt_pk_bf16_f32 %0, %1, %2" : "=v"(Wa[ni]) : "v"(p[ni * 4 + 0]), "v"(p[ni * 4 + 1]));
                asm("v_cvt_pk_bf16_f32 %0, %1, %2" : "=v"(Wb[ni]) : "v"(p[ni * 4 + 2]), "v"(p[ni * 4 + 3]));
            }
            unsigned int a0 = Wa[0], a1 = Wa[1], b0 = Wb[0], b1 = Wb[1];
            unsigned int c0 = Wa[2], c1 = Wa[3], d0 = Wb[2], d1 = Wb[3];
            asm("v_permlane32_swap_b32 %0, %1" : "+v"(a0), "+v"(a1));
            asm("v_permlane16_swap_b32 %0, %1" : "+v"(a0), "+v"(a1));
            asm("v_permlane32_swap_b32 %0, %1" : "+v"(b0), "+v"(b1));
            asm("v_permlane16_swap_b32 %0, %1" : "+v"(b0), "+v"(b1));
            asm("v_permlane32_swap_b32 %0, %1" : "+v"(c0), "+v"(c1));
            asm("v_permlane16_swap_b32 %0, %1" : "+v"(c0), "+v"(c1));
            asm("v_permlane32_swap_b32 %0, %1" : "+v"(d0), "+v"(d1));
            asm("v_permlane16_swap_b32 %0, %1" : "+v"(d0), "+v"(d1));
            pk[gr][0].u[0] = a0; pk[gr][0].u[1] = b0; pk[gr][0].u[2] = a1; pk[gr][0].u[3] = b1;
            pk[gr][1].u[0] = c0; pk[gr][1].u[1] = d0; pk[gr][1].u[2] = c1; pk[gr][1].u[3] = d1;
        }

        // PV for all 4 groups, vf read once
        __builtin_amdgcn_s_setprio(1);
        #pragma unroll
        for (int ks = 0; ks < 2; ks++) {
            #pragma unroll
            for (int ni = 0; ni < 4; ni++) {
                int vrow = ni * 16 + qcol;
                int slot = (ks * 4 + g) ^ (vrow & 7);
                short8 vf = *reinterpret_cast<const short8*>(&Vb[vrow * 64 + slot * 8]);
                #pragma unroll
                for (int gr = 0; gr < 4; gr++)
                    cacc[gr][ni] = __builtin_amdgcn_mfma_f32_16x16x32_bf16(pk[gr][ks].s, vf, cacc[gr][ni], 0, 0, 0);
            }
        }
        __builtin_amdgcn_s_setprio(0);
    }

    #pragma unroll
    for (int gr = 0; gr < 4; gr++) {
        l[gr] += __shfl_xor(l[gr], 16, 64);
        l[gr] += __shfl_xor(l[gr], 32, 64);
    }

    #pragma unroll
    for (int r = 0; r < 4; r++) {
        #pragma unroll
        for (int gr = 0; gr < 4; gr++) {
            float lv = __shfl(l[gr], (g << 2) + r, 64);
            float inv = 1.f / lv;
            int qrow = q0w + gr * 64 + (g << 2) + r;
            #pragma unroll
            for (int ni = 0; ni < 4; ni++) {
                int dh = ni * 16 + qcol;
                Ctxb[(size_t)(b * S_ + qrow) * D_ + h * DH_ + dh] = f32_to_bf16_rne(cacc[gr][ni][r] * inv);
            }
        }
    }
}

// ---------------- residual + LayerNorm (bf16 ctx + bf16 x) ----------------
__global__ __launch_bounds__(256) void ln_kernel(const unsigned short* __restrict__ Ctxb,
                                                 const unsigned short* __restrict__ Xb,
                                                 const float* __restrict__ gamma,
                                                 const float* __restrict__ beta,
                                                 float* __restrict__ out) {
    const int row = blockIdx.x;
    const int tid = threadIdx.x;
    const int lane = tid & 63, w = tid >> 6;

    ushort4 c4 = reinterpret_cast<const ushort4*>(Ctxb + (size_t)row * D_)[tid];
    ushort4 x4 = reinterpret_cast<const ushort4*>(Xb + (size_t)row * D_)[tid];
    float4 v;
    v.x = __uint_as_float((unsigned)c4.x << 16) + __uint_as_float((unsigned)x4.x << 16);
    v.y = __uint_as_float((unsigned)c4.y << 16) + __uint_as_float((unsigned)x4.y << 16);
    v.z = __uint_as_float((unsigned)c4.z << 16) + __uint_as_float((unsigned)x4.z << 16);
    v.w = __uint_as_float((unsigned)c4.w << 16) + __uint_as_float((unsigned)x4.w << 16);

    float s = v.x + v.y + v.z + v.w;
    float ss = v.x * v.x + v.y * v.y + v.z * v.z + v.w * v.w;
    for (int off = 1; off < 64; off <<= 1) {
        s += __shfl_xor(s, off, 64);
        ss += __shfl_xor(ss, off, 64);
    }
    __shared__ float sbuf[4], ssbuf[4];
    if (lane == 0) { sbuf[w] = s; ssbuf[w] = ss; }
    __syncthreads();
    s = sbuf[0] + sbuf[1] + sbuf[2] + sbuf[3];
    ss = ssbuf[0] + ssbuf[1] + ssbuf[2] + ssbuf[3];

    float mean = s * (1.f / D_);
    float var = ss * (1.f / D_) - mean * mean;
    float rstd = rsqrtf(var + 1e-5f);

    const float4 gm = reinterpret_cast<const float4*>(gamma)[tid];
    const float4 bt = reinterpret_cast<const float4*>(beta)[tid];
    float4 o;
    o.x = (v.x - mean) * rstd * gm.x + bt.x;
    o.y = (v.y - mean) * rstd * gm.y + bt.y;
    o.z = (v.z - mean) * rstd * gm.z + bt.z;
    o.w = (v.w - mean) * rstd * gm.w + bt.w;
    reinterpret_cast<float4*>(out + (size_t)row * D_)[tid] = o;
}

extern "C" void kernel_launch(void* const* d_in, const int* in_sizes, int n_in,
                              void* d_out, int out_size, void* d_ws, size_t ws_size,
                              hipStream_t stream) {
    const float* x       = (const float*)d_in[0];
    const int*   lengths = (const int*)d_in[1];
    const float* Wq      = (const float*)d_in[2];
    const float* bq      = (const float*)d_in[3];
    const float* Wk      = (const float*)d_in[4];
    const float* bk      = (const float*)d_in[5];
    const float* Wv      = (const float*)d_in[6];
    const float* bv      = (const float*)d_in[7];
    const float* gamma   = (const float*)d_in[8];
    const float* beta    = (const float*)d_in[9];
    float* out = (float*)d_out;

    char* ws = (char*)d_ws;
    unsigned short* xb    = (unsigned short*)(ws);                 // 16 MB
    unsigned short* Wball = (unsigned short*)(ws + 16777216);      // 6 MB
    unsigned short* QKV   = (unsigned short*)(ws + 23068672);      // 32 MB (Q,K only)
    unsigned short* Vt    = (unsigned short*)(ws + 56623104);      // 16 MB
    unsigned short* Ctxb  = (unsigned short*)(ws + 73400320);      // 16 MB (end 90.2 MB)

    // allow 144 KB dynamic LDS for gemm_qkv (host-side, capture-safe, idempotent)
    (void)hipFuncSetAttribute((const void*)gemm_qkv,
                              hipFuncAttributeMaxDynamicSharedMemorySize, 147456);

    cvt_all<<<5632, 256, 0, stream>>>(x, Wq, Wk, Wv, xb, Wball);

    gemm_qkv<<<256, 512, 147456, stream>>>(xb, Wball, bq, bk, bv, lengths, QKV, Vt);

    attn_kernel<<<512, 256, 0, stream>>>(QKV, Vt, Ctxb);

    ln_kernel<<<8192, 256, 0, stream>>>(Ctxb, xb, gamma, beta, out);
}